// Round 11
// baseline (913.758 us; speedup 1.0000x reference)
//
#include <hip/hip_runtime.h>
#include <hip/hip_bf16.h>

// out[b,s,o] = sum_k x[b,s,k] * W[o,k] + bias[o],  W[o,k] = sum_d codebook[idx[o,d]] * rot[k,d]
// R11 = R8 chassis + (1) counted-lgkm interleave inside each phase: reads issue in a PINNED
// order (sched_barrier(0) between groups so lgkmcnt counting matches issue order), then
// lgkmcnt(3)/(2)/(1)/(0) each releasing one 4-MFMA group (mf-outer) -> read drain hides under
// MFMA instead of a full lgkmcnt(0) stall (the suspected 505cy/phase serializer; R10 probe
// confirmed MFMA floor = 620cy/phase, so the gap is all memory+sync).
// (2) gemm_skel probe (grid 2048, own rocprof row): R8-exact mem+sync skeleton, MFMA replaced
// by asm register sinks (rule 17) -> measures whether mem+sync alone costs ~505cy/phase.

typedef __attribute__((ext_vector_type(8))) __bf16 bf16x8;
typedef __attribute__((ext_vector_type(4))) float f32x4;

#define GLOAD_LDS16(g, l)                                                        \
  __builtin_amdgcn_global_load_lds((__attribute__((address_space(1))) void*)(g), \
                                   (__attribute__((address_space(3))) void*)(l), \
                                   16, 0, 0)

#define SB() __builtin_amdgcn_sched_barrier(0)

// ---------------- conversion kernels ----------------

__global__ __launch_bounds__(256) void cvt_f32_bf16(const float* __restrict__ in,
                                                    __hip_bfloat16* __restrict__ out, int n4) {
  int i = blockIdx.x * 256 + threadIdx.x;
  if (i >= n4) return;
  float4 v = *(const float4*)(in + (size_t)i * 4);
  union { __hip_bfloat16 h[4]; ushort4 u; } o;
  o.h[0] = __float2bfloat16(v.x);
  o.h[1] = __float2bfloat16(v.y);
  o.h[2] = __float2bfloat16(v.z);
  o.h[3] = __float2bfloat16(v.w);
  *(ushort4*)((unsigned short*)out + (size_t)i * 4) = o.u;
}

__global__ __launch_bounds__(256) void dequant_bf16(const int* __restrict__ idx,
                                                    const float* __restrict__ cb,
                                                    __hip_bfloat16* __restrict__ out, int n4) {
  __shared__ __hip_bfloat16 scb[16];
  if (threadIdx.x < 16) scb[threadIdx.x] = __float2bfloat16(cb[threadIdx.x]);
  __syncthreads();
  int i = blockIdx.x * 256 + threadIdx.x;
  if (i >= n4) return;
  int4 v = *(const int4*)(idx + (size_t)i * 4);
  union { __hip_bfloat16 h[4]; ushort4 u; } o;
  o.h[0] = scb[v.x & 15];
  o.h[1] = scb[v.y & 15];
  o.h[2] = scb[v.z & 15];
  o.h[3] = scb[v.w & 15];
  *(ushort4*)((unsigned short*)out + (size_t)i * 4) = o.u;
}

// ---------------- 256^2 4-phase NT bf16 GEMM, counted-lgkm interleave ----------------

template <bool OUT_BF16>
__global__ __launch_bounds__(512, 2) void gemm256(const __hip_bfloat16* __restrict__ A,
                                                  const __hip_bfloat16* __restrict__ B,
                                                  void* __restrict__ Cv,
                                                  const float* __restrict__ bias,
                                                  int M, int N, int K) {
  __shared__ __align__(16) char smem[131072];

  const int nbn = N >> 8;
  const int nwg = (M >> 8) * nbn;
  const int bid0 = blockIdx.x;
  const int cpx = nwg >> 3;
  const int bid = (bid0 & 7) * cpx + (bid0 >> 3);
  const int m0 = (bid / nbn) << 8;
  const int n0 = (bid % nbn) << 8;

  const int tid = (int)threadIdx.x;
  const int lane = tid & 63;
  const int w = tid >> 6;
  const int wr = w >> 2;
  const int wc = w & 3;
  const int fr = lane & 15;
  const int fq = lane >> 4;

  const int srow = lane >> 3;
  const int scol = ((lane & 7) ^ srow) << 3;

  const __hip_bfloat16* Ab = A + (size_t)m0 * K;
  const __hip_bfloat16* Bb = B + (size_t)n0 * K;

  const int NT = K >> 6;

  f32x4 acc[8][4];
#pragma unroll
  for (int i = 0; i < 8; ++i)
#pragma unroll
    for (int j = 0; j < 4; ++j) acc[i][j] = (f32x4){0.f, 0.f, 0.f, 0.f};

  auto stage = [&](int s) {
    const int t = s >> 2, kind = s & 3;
    const __hip_bfloat16* g = (kind < 2) ? Ab : Bb;
    char* region = smem + ((kind < 2) ? 0 : 65536) + (t & 1) * 32768 + (kind & 1) * 16384;
    const int grow = (kind & 1) * 128 + w * 16 + srow;
    const int k0 = t << 6;
#pragma unroll
    for (int j = 0; j < 2; ++j)
      GLOAD_LDS16(g + (size_t)(grow + j * 8) * K + (k0 + scol), region + w * 2048 + j * 1024);
  };

  const int sw = (fr & 7) << 4;

  auto ldA = [&](int b, int mh, int mf, int kk) -> bf16x8 {
    const int row = wr * 128 + mh * 64 + mf * 16 + fr;
    const int byte = b * 32768 + row * 128 + ((kk * 64 + fq * 16) ^ sw);
    return *(const bf16x8*)(smem + byte);
  };
  auto ldB = [&](int b, int nf, int kk) -> bf16x8 {
    const int row = wc * 64 + nf * 16 + fr;
    const int byte = 65536 + b * 32768 + row * 128 + ((kk * 64 + fq * 16) ^ sw);
    return *(const bf16x8*)(smem + byte);
  };

  bf16x8 afA[4], afB[4], bk0[4], bk1[4];

  // one 4-MFMA group: acc[base+mf][0..3] += af[mf] x bk[0..3]
  auto group = [&](int base, int mf, bf16x8 (&af)[4], bf16x8 (&bk)[4]) {
#pragma unroll
    for (int nf = 0; nf < 4; ++nf)
      acc[base + mf][nf] =
          __builtin_amdgcn_mfma_f32_16x16x32_bf16(af[mf], bk[nf], acc[base + mf][nf], 0, 0, 0);
  };

  // prologue: tile0 fully + B(1)
  stage(0); stage(1); stage(2); stage(3);
  stage(6); stage(7);

  for (int T = 0; T < NT; ++T) {
    const int b = T & 1;
    const bool pf1 = (T + 1 < NT);
    const bool pf2 = (T + 2 < NT);

    // ---- ph0: vmcnt certify; BAR; pinned reads (bk0 x4, then afA one-by-one); stage;
    //           counted lgkm steps releasing mf-groups
    if (T + 1 == NT) {
      asm volatile("s_waitcnt vmcnt(0)" ::: "memory");
    } else {
      asm volatile("s_waitcnt vmcnt(4)" ::: "memory");
    }
    __builtin_amdgcn_s_barrier();
#pragma unroll
    for (int nf = 0; nf < 4; ++nf) bk0[nf] = ldB(b, nf, 0);
    SB();
    afA[0] = ldA(b, 0, 0, 0); SB();
    afA[1] = ldA(b, 0, 1, 0); SB();
    afA[2] = ldA(b, 0, 2, 0); SB();
    afA[3] = ldA(b, 0, 3, 0); SB();
    if (pf1) stage(4 * (T + 1) + 0);
    asm volatile("s_waitcnt lgkmcnt(3)"); SB();
    __builtin_amdgcn_s_setprio(1);
    group(0, 0, afA, bk0);
    asm volatile("s_waitcnt lgkmcnt(2)"); SB();
    group(0, 1, afA, bk0);
    asm volatile("s_waitcnt lgkmcnt(1)"); SB();
    group(0, 2, afA, bk0);
    asm volatile("s_waitcnt lgkmcnt(0)"); SB();
    group(0, 3, afA, bk0);
    __builtin_amdgcn_s_setprio(0);

    // ph1 reads (pinned), issued after ph0's MFMA, pre-BAR
#pragma unroll
    for (int nf = 0; nf < 4; ++nf) bk1[nf] = ldB(b, nf, 1);
    SB();
    afB[0] = ldA(b, 0, 0, 1); SB();
    afB[1] = ldA(b, 0, 1, 1); SB();
    afB[2] = ldA(b, 0, 2, 1); SB();
    afB[3] = ldA(b, 0, 3, 1); SB();
    __builtin_amdgcn_s_barrier();
    if (pf1) stage(4 * (T + 1) + 1);
    asm volatile("s_waitcnt lgkmcnt(3)"); SB();
    __builtin_amdgcn_s_setprio(1);
    group(0, 0, afB, bk1);
    asm volatile("s_waitcnt lgkmcnt(2)"); SB();
    group(0, 1, afB, bk1);
    asm volatile("s_waitcnt lgkmcnt(1)"); SB();
    group(0, 2, afB, bk1);
    asm volatile("s_waitcnt lgkmcnt(0)"); SB();
    group(0, 3, afB, bk1);
    __builtin_amdgcn_s_setprio(0);

    // ph2 reads (4, pinned one-by-one), pre-BAR
    afA[0] = ldA(b, 1, 0, 0); SB();
    afA[1] = ldA(b, 1, 1, 0); SB();
    afA[2] = ldA(b, 1, 2, 0); SB();
    afA[3] = ldA(b, 1, 3, 0); SB();
    __builtin_amdgcn_s_barrier();
    if (pf2) stage(4 * (T + 2) + 2);
    asm volatile("s_waitcnt lgkmcnt(3)"); SB();
    __builtin_amdgcn_s_setprio(1);
    group(4, 0, afA, bk0);
    asm volatile("s_waitcnt lgkmcnt(2)"); SB();
    group(4, 1, afA, bk0);
    asm volatile("s_waitcnt lgkmcnt(1)"); SB();
    group(4, 2, afA, bk0);
    asm volatile("s_waitcnt lgkmcnt(0)"); SB();
    group(4, 3, afA, bk0);
    __builtin_amdgcn_s_setprio(0);

    // ph3 reads (4, pinned), pre-BAR
    afB[0] = ldA(b, 1, 0, 1); SB();
    afB[1] = ldA(b, 1, 1, 1); SB();
    afB[2] = ldA(b, 1, 2, 1); SB();
    afB[3] = ldA(b, 1, 3, 1); SB();
    __builtin_amdgcn_s_barrier();
    if (pf2) stage(4 * (T + 2) + 3);
    asm volatile("s_waitcnt lgkmcnt(3)"); SB();
    __builtin_amdgcn_s_setprio(1);
    group(4, 0, afB, bk1);
    asm volatile("s_waitcnt lgkmcnt(2)"); SB();
    group(4, 1, afB, bk1);
    asm volatile("s_waitcnt lgkmcnt(1)"); SB();
    group(4, 2, afB, bk1);
    asm volatile("s_waitcnt lgkmcnt(0)"); SB();
    group(4, 3, afB, bk1);
    __builtin_amdgcn_s_setprio(0);
    // next iteration's ph0 vmcnt+barrier closes the tile
  }

  // ---- epilogue
  if constexpr (OUT_BF16) {
    __hip_bfloat16* C = (__hip_bfloat16*)Cv;
#pragma unroll
    for (int mi = 0; mi < 8; ++mi)
#pragma unroll
      for (int ni = 0; ni < 4; ++ni) {
        const size_t row = (size_t)(m0 + wr * 128 + (mi >> 2) * 64 + (mi & 3) * 16 + fq * 4);
        const int col = n0 + wc * 64 + ni * 16 + fr;
#pragma unroll
        for (int v = 0; v < 4; ++v) C[(row + v) * N + col] = __float2bfloat16(acc[mi][ni][v]);
      }
  } else {
    float* C = (float*)Cv;
    float bv[4];
#pragma unroll
    for (int ni = 0; ni < 4; ++ni) bv[ni] = bias[n0 + wc * 64 + ni * 16 + fr];
#pragma unroll
    for (int mi = 0; mi < 8; ++mi)
#pragma unroll
      for (int ni = 0; ni < 4; ++ni) {
        const size_t row = (size_t)(m0 + wr * 128 + (mi >> 2) * 64 + (mi & 3) * 16 + fq * 4);
        const int col = n0 + wc * 64 + ni * 16 + fr;
#pragma unroll
        for (int v = 0; v < 4; ++v) C[(row + v) * N + col] = acc[mi][ni][v] + bv[ni];
      }
  }
}

// ---------------- gemm_skel: R8-exact memory+sync skeleton, MFMA -> register sinks ---------
// Measures mem+sync cost per phase with NO matrix work. grid 2048 (8 rounds/CU) so it cracks
// the top-5 rocprof cutoff if mem+sync is the additive ~505cy/phase (expected ~420us);
// absence from top-5 => mem+sync < ~300cy/phase => serializer is MFMA<->mem interaction.

__global__ __launch_bounds__(512, 2) void gemm_skel(const __hip_bfloat16* __restrict__ A,
                                                    const __hip_bfloat16* __restrict__ B,
                                                    __hip_bfloat16* __restrict__ C,
                                                    int K) {
  __shared__ __align__(16) char smem[131072];

  const int bid0 = blockIdx.x;
  const int m0 = (bid0 & 15) << 8;          // own mapping, all within 4096^2
  const int n0 = ((bid0 >> 4) & 15) << 8;   // blocks >=256 recompute tiles (write zeros: benign)
  const int N = 4096;

  const int tid = (int)threadIdx.x;
  const int lane = tid & 63;
  const int w = tid >> 6;
  const int wr = w >> 2;
  const int wc = w & 3;
  const int fr = lane & 15;
  const int fq = lane >> 4;

  const int srow = lane >> 3;
  const int scol = ((lane & 7) ^ srow) << 3;

  const __hip_bfloat16* Ab = A + (size_t)m0 * K;
  const __hip_bfloat16* Bb = B + (size_t)n0 * K;

  const int NT = K >> 6;

  f32x4 acc[8][4];
#pragma unroll
  for (int i = 0; i < 8; ++i)
#pragma unroll
    for (int j = 0; j < 4; ++j) acc[i][j] = (f32x4){0.f, 0.f, 0.f, 0.f};

  auto stage = [&](int s) {
    const int t = s >> 2, kind = s & 3;
    const __hip_bfloat16* g = (kind < 2) ? Ab : Bb;
    char* region = smem + ((kind < 2) ? 0 : 65536) + (t & 1) * 32768 + (kind & 1) * 16384;
    const int grow = (kind & 1) * 128 + w * 16 + srow;
    const int k0 = t << 6;
#pragma unroll
    for (int j = 0; j < 2; ++j)
      GLOAD_LDS16(g + (size_t)(grow + j * 8) * K + (k0 + scol), region + w * 2048 + j * 1024);
  };

  const int sw = (fr & 7) << 4;

  auto ldA = [&](int b, int mh, int mf, int kk) -> bf16x8 {
    const int row = wr * 128 + mh * 64 + mf * 16 + fr;
    const int byte = b * 32768 + row * 128 + ((kk * 64 + fq * 16) ^ sw);
    return *(const bf16x8*)(smem + byte);
  };
  auto ldB = [&](int b, int nf, int kk) -> bf16x8 {
    const int row = wc * 64 + nf * 16 + fr;
    const int byte = 65536 + b * 32768 + row * 128 + ((kk * 64 + fq * 16) ^ sw);
    return *(const bf16x8*)(smem + byte);
  };

#define SINK8(a, b2)                                                                     \
  asm volatile("" ::"v"((a)[0]), "v"((a)[1]), "v"((a)[2]), "v"((a)[3]), "v"((b2)[0]),    \
               "v"((b2)[1]), "v"((b2)[2]), "v"((b2)[3]))
#define SINK4(a) asm volatile("" ::"v"((a)[0]), "v"((a)[1]), "v"((a)[2]), "v"((a)[3]))

  stage(0); stage(1); stage(2); stage(3);
  stage(6); stage(7);

  bf16x8 afA[4], afB[4], bk0[4], bk1[4];

  for (int T = 0; T < NT; ++T) {
    const int b = T & 1;
    const bool pf1 = (T + 1 < NT);
    const bool pf2 = (T + 2 < NT);

    // ph0 (R8-exact: full lgkm(0) drain, no MFMA)
    if (T + 1 == NT) {
      asm volatile("s_waitcnt vmcnt(0)" ::: "memory");
    } else {
      asm volatile("s_waitcnt vmcnt(4)" ::: "memory");
    }
    __builtin_amdgcn_s_barrier();
#pragma unroll
    for (int mf = 0; mf < 4; ++mf) afA[mf] = ldA(b, 0, mf, 0);
#pragma unroll
    for (int nf = 0; nf < 4; ++nf) bk0[nf] = ldB(b, nf, 0);
    if (pf1) stage(4 * (T + 1) + 0);
    asm volatile("s_waitcnt lgkmcnt(0)");
    SB();
    __builtin_amdgcn_s_setprio(1);
    SINK8(afA, bk0);
    __builtin_amdgcn_s_setprio(0);

    // ph1
#pragma unroll
    for (int mf = 0; mf < 4; ++mf) afB[mf] = ldA(b, 0, mf, 1);
#pragma unroll
    for (int nf = 0; nf < 4; ++nf) bk1[nf] = ldB(b, nf, 1);
    __builtin_amdgcn_s_barrier();
    if (pf1) stage(4 * (T + 1) + 1);
    asm volatile("s_waitcnt lgkmcnt(0)");
    SB();
    __builtin_amdgcn_s_setprio(1);
    SINK8(afB, bk1);
    __builtin_amdgcn_s_setprio(0);

    // ph2
#pragma unroll
    for (int mf = 0; mf < 4; ++mf) afA[mf] = ldA(b, 1, mf, 0);
    __builtin_amdgcn_s_barrier();
    if (pf2) stage(4 * (T + 2) + 2);
    asm volatile("s_waitcnt lgkmcnt(0)");
    SB();
    __builtin_amdgcn_s_setprio(1);
    SINK4(afA);
    __builtin_amdgcn_s_setprio(0);

    // ph3
#pragma unroll
    for (int mf = 0; mf < 4; ++mf) afB[mf] = ldA(b, 1, mf, 1);
    __builtin_amdgcn_s_barrier();
    if (pf2) stage(4 * (T + 2) + 3);
    asm volatile("s_waitcnt lgkmcnt(0)");
    SB();
    __builtin_amdgcn_s_setprio(1);
    SINK4(afB);
    __builtin_amdgcn_s_setprio(0);
  }

  // epilogue writes acc (zeros) -> scratch, keeps structure cost comparable
#pragma unroll
  for (int mi = 0; mi < 8; ++mi)
#pragma unroll
    for (int ni = 0; ni < 4; ++ni) {
      const size_t row = (size_t)(m0 + wr * 128 + (mi >> 2) * 64 + (mi & 3) * 16 + fq * 4);
      const int col = n0 + wc * 64 + ni * 16 + fr;
#pragma unroll
      for (int v = 0; v < 4; ++v) C[(row + v) * N + col] = __float2bfloat16(acc[mi][ni][v]);
    }
#undef SINK8
#undef SINK4
}

// ---------------- launch ----------------

extern "C" void kernel_launch(void* const* d_in, const int* in_sizes, int n_in,
                              void* d_out, int out_size, void* d_ws, size_t ws_size,
                              hipStream_t stream) {
  const float* x = (const float*)d_in[0];        // [B,S,D] = [4,2048,4096] f32
  const int* indices = (const int*)d_in[1];      // [O,D] = [4096,4096] i32
  const float* codebook = (const float*)d_in[2]; // [16] f32
  const float* rot = (const float*)d_in[3];      // [K,D] = [4096,4096] f32
  const float* bias = (const float*)d_in[4];     // [O] f32
  float* out = (float*)d_out;                    // [B*S, O] f32

  const int D = 4096, O = 4096;
  const int M = in_sizes[0] / D;  // 8192

  char* ws = (char*)d_ws;
  __hip_bfloat16* Xb = (__hip_bfloat16*)ws;                          // 64MB: [M,D] bf16
  __hip_bfloat16* Rb = (__hip_bfloat16*)(ws + ((size_t)64 << 20));   // 32MB: [K,D] bf16
  __hip_bfloat16* Wr = (__hip_bfloat16*)(ws + ((size_t)96 << 20));   // 32MB: [O,D] bf16
  __hip_bfloat16* Wb = (__hip_bfloat16*)(ws + ((size_t)128 << 20));  // 32MB: [O,K] bf16

  cvt_f32_bf16<<<(M * D / 4 + 255) / 256, 256, 0, stream>>>(x, Xb, M * D / 4);
  cvt_f32_bf16<<<(4096 * 4096 / 4 + 255) / 256, 256, 0, stream>>>(rot, Rb, 4096 * 4096 / 4);
  dequant_bf16<<<(4096 * 4096 / 4 + 255) / 256, 256, 0, stream>>>(indices, codebook, Wr,
                                                                  4096 * 4096 / 4);

  // GEMM1: Wb[o,k] = sum_d Wr[o,d] * Rb[k,d]   (4096^3, bf16 out)
  gemm256<true><<<dim3((O / 256) * (4096 / 256)), 512, 0, stream>>>(Wr, Rb, Wb, nullptr, O, 4096,
                                                                    D);
  // GEMM2: out[m,o] = sum_k Xb[m,k] * Wb[o,k] + bias[o]   (8192x4096x4096, f32 out)
  gemm256<false><<<dim3((M / 256) * (O / 256)), 512, 0, stream>>>(Xb, Wb, out, bias, M, O, 4096);

  // R11 probe: mem+sync skeleton (R8 structure, no MFMA), runs AFTER GEMM2 (reads Xb/Rb which
  // are stable; writes zeros to Wb which GEMM1 rewrites next call -> deterministic).
  gemm_skel<<<2048, 512, 0, stream>>>(Xb, Rb, Wb, 4096);
}

// Round 12
// 411.869 us; speedup vs baseline: 2.2186x; 2.2186x over previous
//
#include <hip/hip_runtime.h>
#include <hip/hip_bf16.h>

// out[b,s,o] = sum_k x[b,s,k] * W[o,k] + bias[o],  W[o,k] = sum_d codebook[idx[o,d]] * rot[k,d]
// R12 = R8 chassis (verified 437us, absmax 2.0) + HK technique #8 "precomputed swizzled LDS
// offsets": the read-side XOR swizzle is lane-separable
//   (kk*64 + fq*16) ^ ((fr&7)<<4) == ((fq ^ (fr&3))<<4) + 64*(kk ^ ((fr>>2)&1))
// so 4 per-lane base pointers (kk variant baked in) + T-loop unrolled x2 (compile-time buf)
// turn EVERY ds_read into `ds_read_b128 v, vaddr offset:LITERAL` with zero per-read VALU.
// Also: setprio removed (m190: hurts lockstep schedules). Sync structure byte-identical to R8
// (1 barrier/phase, reads pre-barrier, stage post-barrier, counted vmcnt(4), lgkm(0)+SB rule18)
// -> all R8 hazard audits carry over unchanged.

typedef __attribute__((ext_vector_type(8))) __bf16 bf16x8;
typedef __attribute__((ext_vector_type(4))) float f32x4;

#define GLOAD_LDS16(g, l)                                                        \
  __builtin_amdgcn_global_load_lds((__attribute__((address_space(1))) void*)(g), \
                                   (__attribute__((address_space(3))) void*)(l), \
                                   16, 0, 0)

#define SB() __builtin_amdgcn_sched_barrier(0)

// ---------------- conversion kernels ----------------

__global__ __launch_bounds__(256) void cvt_f32_bf16(const float* __restrict__ in,
                                                    __hip_bfloat16* __restrict__ out, int n4) {
  int i = blockIdx.x * 256 + threadIdx.x;
  if (i >= n4) return;
  float4 v = *(const float4*)(in + (size_t)i * 4);
  union { __hip_bfloat16 h[4]; ushort4 u; } o;
  o.h[0] = __float2bfloat16(v.x);
  o.h[1] = __float2bfloat16(v.y);
  o.h[2] = __float2bfloat16(v.z);
  o.h[3] = __float2bfloat16(v.w);
  *(ushort4*)((unsigned short*)out + (size_t)i * 4) = o.u;
}

__global__ __launch_bounds__(256) void dequant_bf16(const int* __restrict__ idx,
                                                    const float* __restrict__ cb,
                                                    __hip_bfloat16* __restrict__ out, int n4) {
  __shared__ __hip_bfloat16 scb[16];
  if (threadIdx.x < 16) scb[threadIdx.x] = __float2bfloat16(cb[threadIdx.x]);
  __syncthreads();
  int i = blockIdx.x * 256 + threadIdx.x;
  if (i >= n4) return;
  int4 v = *(const int4*)(idx + (size_t)i * 4);
  union { __hip_bfloat16 h[4]; ushort4 u; } o;
  o.h[0] = scb[v.x & 15];
  o.h[1] = scb[v.y & 15];
  o.h[2] = scb[v.z & 15];
  o.h[3] = scb[v.w & 15];
  *(ushort4*)((unsigned short*)out + (size_t)i * 4) = o.u;
}

// ---------------- 256^2 4-phase (1-barrier) NT bf16 GEMM, precomputed LDS offsets ----------

template <bool OUT_BF16>
__global__ __launch_bounds__(512, 2) void gemm256(const __hip_bfloat16* __restrict__ A,
                                                  const __hip_bfloat16* __restrict__ B,
                                                  void* __restrict__ Cv,
                                                  const float* __restrict__ bias,
                                                  int M, int N, int K) {
  __shared__ __align__(16) char smem[131072];

  const int nbn = N >> 8;
  const int nwg = (M >> 8) * nbn;
  const int bid0 = blockIdx.x;
  const int cpx = nwg >> 3;  // nwg % 8 == 0 for our shapes -> bijective XCD swizzle
  const int bid = (bid0 & 7) * cpx + (bid0 >> 3);
  const int m0 = (bid / nbn) << 8;
  const int n0 = (bid % nbn) << 8;

  const int tid = (int)threadIdx.x;
  const int lane = tid & 63;
  const int w = tid >> 6;
  const int wr = w >> 2;
  const int wc = w & 3;
  const int fr = lane & 15;
  const int fq = lane >> 4;

  const int srow = lane >> 3;
  const int scol = ((lane & 7) ^ srow) << 3;

  const __hip_bfloat16* Ab = A + (size_t)m0 * K;
  const __hip_bfloat16* Bb = B + (size_t)n0 * K;

  const int NT = K >> 6;

  f32x4 acc[8][4];
#pragma unroll
  for (int i = 0; i < 8; ++i)
#pragma unroll
    for (int j = 0; j < 4; ++j) acc[i][j] = (f32x4){0.f, 0.f, 0.f, 0.f};

  auto stage = [&](int s) {
    const int t = s >> 2, kind = s & 3;
    const __hip_bfloat16* g = (kind < 2) ? Ab : Bb;
    char* region = smem + ((kind < 2) ? 0 : 65536) + (t & 1) * 32768 + (kind & 1) * 16384;
    const int grow = (kind & 1) * 128 + w * 16 + srow;
    const int k0 = t << 6;
#pragma unroll
    for (int j = 0; j < 2; ++j)
      GLOAD_LDS16(g + (size_t)(grow + j * 8) * K + (k0 + scol), region + w * 2048 + j * 1024);
  };

  // Precomputed per-lane LDS read bases (swizzle baked in; kk variant in the pointer):
  //   byte(b,mh,mf,kk) = b*32768 + (wr*128+mh*64+mf*16+fr)*128 + ((kk*64+fq*16)^((fr&7)<<4))
  //                    = [wr*16384 + fr*128 + ((fq^(fr&3))<<4) + 64*(kk^fr2)]  (lane base)
  //                      + b*32768 + mh*8192 + mf*2048                          (literal)
  const int fr2 = (fr >> 2) & 1;
  const int fcol = (fq ^ (fr & 3)) << 4;
  const char* pA0 = smem + wr * 16384 + fr * 128 + fcol + 64 * fr2;
  const char* pA1 = smem + wr * 16384 + fr * 128 + fcol + 64 * (1 - fr2);
  const char* pB0 = smem + 65536 + wc * 8192 + fr * 128 + fcol + 64 * fr2;
  const char* pB1 = smem + 65536 + wc * 8192 + fr * 128 + fcol + 64 * (1 - fr2);

#define LDA(BUF, MH, MF, KK) \
  (*(const bf16x8*)(((KK) ? pA1 : pA0) + (BUF) * 32768 + (MH) * 8192 + (MF) * 2048))
#define LDB(BUF, NF, KK) (*(const bf16x8*)(((KK) ? pB1 : pB0) + (BUF) * 32768 + (NF) * 2048))

  // prologue: tile0 fully + B(1); loop ph0's vmcnt+BAR certifies tile0
  stage(0); stage(1); stage(2); stage(3);
  stage(6); stage(7);

  bf16x8 afA[4], afB[4], bk0[4], bk1[4];

#define TILE_BODY(BUF, T)                                                                     \
  {                                                                                           \
    const bool pf1 = ((T) + 1 < NT);                                                          \
    const bool pf2 = ((T) + 2 < NT);                                                          \
    /* ph0: vmcnt certify; BAR; reads post-bar; stage A0(T+1); lgkm; MFMA */                  \
    if ((T) + 1 == NT) {                                                                      \
      asm volatile("s_waitcnt vmcnt(0)" ::: "memory");                                        \
    } else {                                                                                  \
      asm volatile("s_waitcnt vmcnt(4)" ::: "memory");                                        \
    }                                                                                         \
    __builtin_amdgcn_s_barrier();                                                             \
    _Pragma("unroll") for (int mf = 0; mf < 4; ++mf) afA[mf] = LDA(BUF, 0, mf, 0);            \
    _Pragma("unroll") for (int nf = 0; nf < 4; ++nf) bk0[nf] = LDB(BUF, nf, 0);               \
    if (pf1) stage(4 * ((T) + 1) + 0);                                                        \
    asm volatile("s_waitcnt lgkmcnt(0)");                                                     \
    SB();                                                                                     \
    _Pragma("unroll") for (int nf = 0; nf < 4; ++nf)                                          \
        _Pragma("unroll") for (int mf = 0; mf < 4; ++mf)                                      \
            acc[mf][nf] =                                                                     \
                __builtin_amdgcn_mfma_f32_16x16x32_bf16(afA[mf], bk0[nf], acc[mf][nf], 0, 0, 0); \
    /* ph1: reads pre-bar; stage A1(T+1) post-bar */                                          \
    _Pragma("unroll") for (int mf = 0; mf < 4; ++mf) afB[mf] = LDA(BUF, 0, mf, 1);            \
    _Pragma("unroll") for (int nf = 0; nf < 4; ++nf) bk1[nf] = LDB(BUF, nf, 1);               \
    __builtin_amdgcn_s_barrier();                                                             \
    if (pf1) stage(4 * ((T) + 1) + 1);                                                        \
    asm volatile("s_waitcnt lgkmcnt(0)");                                                     \
    SB();                                                                                     \
    _Pragma("unroll") for (int nf = 0; nf < 4; ++nf)                                          \
        _Pragma("unroll") for (int mf = 0; mf < 4; ++mf)                                      \
            acc[mf][nf] =                                                                     \
                __builtin_amdgcn_mfma_f32_16x16x32_bf16(afB[mf], bk1[nf], acc[mf][nf], 0, 0, 0); \
    /* ph2: reads pre-bar; stage B0(T+2) post-bar */                                          \
    _Pragma("unroll") for (int mf = 0; mf < 4; ++mf) afA[mf] = LDA(BUF, 1, mf, 0);            \
    __builtin_amdgcn_s_barrier();                                                             \
    if (pf2) stage(4 * ((T) + 2) + 2);                                                        \
    asm volatile("s_waitcnt lgkmcnt(0)");                                                     \
    SB();                                                                                     \
    _Pragma("unroll") for (int nf = 0; nf < 4; ++nf)                                          \
        _Pragma("unroll") for (int mf = 0; mf < 4; ++mf)                                      \
            acc[4 + mf][nf] = __builtin_amdgcn_mfma_f32_16x16x32_bf16(afA[mf], bk0[nf],       \
                                                                      acc[4 + mf][nf], 0, 0, 0); \
    /* ph3: reads pre-bar; stage B1(T+2) post-bar */                                          \
    _Pragma("unroll") for (int mf = 0; mf < 4; ++mf) afB[mf] = LDA(BUF, 1, mf, 1);            \
    __builtin_amdgcn_s_barrier();                                                             \
    if (pf2) stage(4 * ((T) + 2) + 3);                                                        \
    asm volatile("s_waitcnt lgkmcnt(0)");                                                     \
    SB();                                                                                     \
    _Pragma("unroll") for (int nf = 0; nf < 4; ++nf)                                          \
        _Pragma("unroll") for (int mf = 0; mf < 4; ++mf)                                      \
            acc[4 + mf][nf] = __builtin_amdgcn_mfma_f32_16x16x32_bf16(afB[mf], bk1[nf],       \
                                                                      acc[4 + mf][nf], 0, 0, 0); \
  }

  // T-loop unrolled x2: buffer index is compile-time -> all ds_read offsets are literals
  for (int T = 0; T < NT; T += 2) {
    TILE_BODY(0, T);
    TILE_BODY(1, T + 1);
  }
#undef TILE_BODY
#undef LDA
#undef LDB

  // ---- epilogue: C/D layout col = lane&15 (n-side), row = fq*4 + v (m-side)
  if constexpr (OUT_BF16) {
    __hip_bfloat16* C = (__hip_bfloat16*)Cv;
#pragma unroll
    for (int mi = 0; mi < 8; ++mi)
#pragma unroll
      for (int ni = 0; ni < 4; ++ni) {
        const size_t row = (size_t)(m0 + wr * 128 + (mi >> 2) * 64 + (mi & 3) * 16 + fq * 4);
        const int col = n0 + wc * 64 + ni * 16 + fr;
#pragma unroll
        for (int v = 0; v < 4; ++v) C[(row + v) * N + col] = __float2bfloat16(acc[mi][ni][v]);
      }
  } else {
    float* C = (float*)Cv;
    float bv[4];
#pragma unroll
    for (int ni = 0; ni < 4; ++ni) bv[ni] = bias[n0 + wc * 64 + ni * 16 + fr];
#pragma unroll
    for (int mi = 0; mi < 8; ++mi)
#pragma unroll
      for (int ni = 0; ni < 4; ++ni) {
        const size_t row = (size_t)(m0 + wr * 128 + (mi >> 2) * 64 + (mi & 3) * 16 + fq * 4);
        const int col = n0 + wc * 64 + ni * 16 + fr;
#pragma unroll
        for (int v = 0; v < 4; ++v) C[(row + v) * N + col] = acc[mi][ni][v] + bv[ni];
      }
  }
}

// ---------------- launch ----------------

extern "C" void kernel_launch(void* const* d_in, const int* in_sizes, int n_in,
                              void* d_out, int out_size, void* d_ws, size_t ws_size,
                              hipStream_t stream) {
  const float* x = (const float*)d_in[0];        // [B,S,D] = [4,2048,4096] f32
  const int* indices = (const int*)d_in[1];      // [O,D] = [4096,4096] i32
  const float* codebook = (const float*)d_in[2]; // [16] f32
  const float* rot = (const float*)d_in[3];      // [K,D] = [4096,4096] f32
  const float* bias = (const float*)d_in[4];     // [O] f32
  float* out = (float*)d_out;                    // [B*S, O] f32

  const int D = 4096, O = 4096;
  const int M = in_sizes[0] / D;  // 8192

  char* ws = (char*)d_ws;
  __hip_bfloat16* Xb = (__hip_bfloat16*)ws;                          // 64MB: [M,D] bf16
  __hip_bfloat16* Rb = (__hip_bfloat16*)(ws + ((size_t)64 << 20));   // 32MB: [K,D] bf16
  __hip_bfloat16* Wr = (__hip_bfloat16*)(ws + ((size_t)96 << 20));   // 32MB: [O,D] bf16
  __hip_bfloat16* Wb = (__hip_bfloat16*)(ws + ((size_t)128 << 20));  // 32MB: [O,K] bf16

  cvt_f32_bf16<<<(M * D / 4 + 255) / 256, 256, 0, stream>>>(x, Xb, M * D / 4);
  cvt_f32_bf16<<<(4096 * 4096 / 4 + 255) / 256, 256, 0, stream>>>(rot, Rb, 4096 * 4096 / 4);
  dequant_bf16<<<(4096 * 4096 / 4 + 255) / 256, 256, 0, stream>>>(indices, codebook, Wr,
                                                                  4096 * 4096 / 4);

  // GEMM1: Wb[o,k] = sum_d Wr[o,d] * Rb[k,d]   (4096^3, bf16 out)
  gemm256<true><<<dim3((O / 256) * (4096 / 256)), 512, 0, stream>>>(Wr, Rb, Wb, nullptr, O, 4096,
                                                                    D);
  // GEMM2: out[m,o] = sum_k Xb[m,k] * Wb[o,k] + bias[o]   (8192x4096x4096, f32 out)
  gemm256<false><<<dim3((M / 256) * (O / 256)), 512, 0, stream>>>(Xb, Wb, out, bias, M, O, 4096);
}